// Round 6
// baseline (130.564 us; speedup 1.0000x reference)
//
#include <hip/hip_runtime.h>

#define NPIX (128 * 128)
#define CH 64
#define RMID 16
#define KK 9
#define PLANE_B 65536            // bytes per channel plane

typedef float v2f __attribute__((ext_vector_type(2)));

// sched_barrier(0): NOTHING may cross. r12's mask 0x3CF stopped load-sinking
// but let VALU hoist INTO the load batches — same interleave, VGPR stayed 52,
// MLP stayed ~1. Mask 0 forces the 6-8-load batches to be emitted
// contiguously with all results live across the following compute: RA must
// allocate (>52 VGPR), waits become counted-vmcnt, MLP ~= batch size.
#define PIN_BATCH() __builtin_amdgcn_sched_barrier(0)

// Fused involution kernel.
// r13: r9 structure (grid 1024 = 8 bq x 4 octets x 32 strips, 8 groups/blk,
// x4 conv1 dup) + sched_barrier(0) after every load batch.
// Stall model (r9/r11/r12 counters): ~112 VMEM reads/wave at MLP~1, ~700cy
// avg effective latency (x is L3-resident: FETCH 20MB < 33.5MB input) ->
// ~82K stall cy/wave = 66% of wall. Waves dilute weakly (r11: 2x waves ->
// dilation 2.94->2.13). Batching 8 loads per wait divides cluster stall ~8x.
// Pre-commit: VGPR still 52 -> abandon scheduler control, restructure
// (v4f loads / LDS tap-share). VGPR up but time flat -> memory-path
// throughput limit, same pivot.
__global__ __launch_bounds__(256, 4) void invol_fused(
    const float* __restrict__ x,
    const float* __restrict__ w1,
    const float* __restrict__ b1,
    const float* __restrict__ prelu_a,
    const float* __restrict__ w2,
    const float* __restrict__ b2,
    float* __restrict__ out)
{
    const int c    = threadIdx.x & 63;    // column-pair id (cols 2c, 2c+1)
    const int rsub = threadIdx.x >> 6;    // row within strip, wave-uniform

    const int L     = blockIdx.x;         // 0..1023
    const int bq    = L & 7;              // batch == XCD pin
    const int go    = (L >> 3) & 3;       // group-octet (consecutive per XCD)
    const int strip = L >> 5;             // 0..31 (4 rows)

    const int hq  = 4 * strip + rsub;
    const int p0  = hq * 128 + 2 * c;
    const int pb0 = 4 * p0;

    const float* xb  = x + (size_t)bq * CH * NPIX;
    const char*  xbc = (const char*)xb;

    // ---- border masks / clamped row offsets (needed before tap prefetch) --
    const float rm0 = (hq > 0)   ? 1.f : 0.f;
    const float rm2 = (hq < 127) ? 1.f : 0.f;
    const float mL  = (c > 0)    ? 1.f : 0.f;
    const float mR  = (c < 63)   ? 1.f : 0.f;
    const int   ro0 = (hq > 0)   ? -512 : 0;
    const int   ro2 = (hq < 127) ?  512 : 0;

    // ---- prefetch group 0's 6 taps: latency hides under all of conv1 ----
    v2f tA0[2], tA1[2], tA2[2], tE0[2], tE1[2], tE2[2];
    {
        const char* cp0 = xbc + (size_t)(2 * (8 * go)) * PLANE_B;
        const char* cp1 = cp0 + PLANE_B;
        tA0[0] = *(const v2f*)(cp0 + (size_t)(pb0 + ro0));
        tA1[0] = *(const v2f*)(cp0 + (size_t)pb0);
        tA2[0] = *(const v2f*)(cp0 + (size_t)(pb0 + ro2));
        tE0[0] = *(const v2f*)(cp1 + (size_t)(pb0 + ro0));
        tE1[0] = *(const v2f*)(cp1 + (size_t)pb0);
        tE2[0] = *(const v2f*)(cp1 + (size_t)(pb0 + ro2));
    }
    PIN_BATCH();          // group-0 tap batch stays contiguous & early

    // ---- conv1 (pixel-pair layout), octet double-buffered ----
    v2f t2[RMID];
#pragma unroll
    for (int r = 0; r < RMID; ++r) {
        const float b = b1[r];
        t2[r].x = b; t2[r].y = b;
    }
    const float* xp = xb + p0;
    v2f xv[2][8];
#pragma unroll
    for (int k = 0; k < 8; ++k)
        xv[0][k] = *(const v2f*)(xp + (size_t)k * NPIX);
    PIN_BATCH();          // first octet batch contiguous
#pragma unroll
    for (int oct = 0; oct < 8; ++oct) {
        const int cb = oct & 1, nb = cb ^ 1;       // constant after unroll
        if (oct < 7) {
#pragma unroll
            for (int k = 0; k < 8; ++k)
                xv[nb][k] = *(const v2f*)(xp + (size_t)((oct + 1) * 8 + k) * NPIX);
        }
        PIN_BATCH();      // next-octet batch issued before this octet's FMAs
#pragma unroll
        for (int k = 0; k < 8; ++k) {
#pragma unroll
            for (int r = 0; r < RMID; ++r) {
                const float w = w1[r * CH + oct * 8 + k];   // uniform -> s_load
                v2f wv; wv.x = w; wv.y = w;
                t2[r] = __builtin_elementwise_fma(wv, xv[cb][k], t2[r]);
            }
        }
    }
    // PReLU: t = max(t,0) + a*min(t,0)
    {
        const float a = prelu_a[0];
        v2f av; av.x = a; av.y = a;
        v2f z;  z.x = 0.f; z.y = 0.f;
#pragma unroll
        for (int r = 0; r < RMID; ++r) {
            const v2f pos = __builtin_elementwise_max(t2[r], z);
            const v2f neg = __builtin_elementwise_min(t2[r], z);
            t2[r] = __builtin_elementwise_fma(av, neg, pos);
        }
    }

    v2f rm0v; rm0v.x = rm0; rm0v.y = rm0;
    v2f rm2v; rm2v.x = rm2; rm2v.y = rm2;

    char* obc = (char*)(out + (size_t)bq * CH * NPIX);

#pragma unroll
    for (int gi = 0; gi < 8; ++gi) {
        const int g   = 8 * go + gi;               // block-uniform
        const int cur = gi & 1, nxt = cur ^ 1;     // constant after unroll

        // -- row-mask the taps, then shuffle EARLY (lgkm drains under wgen) --
        const v2f A0 = tA0[cur] * rm0v;
        const v2f A1 = tA1[cur];
        const v2f A2 = tA2[cur] * rm2v;
        const v2f E0 = tE0[cur] * rm0v;
        const v2f E1 = tE1[cur];
        const v2f E2 = tE2[cur] * rm2v;

        const float lA0 = __shfl_up(A0.y, 1), rA0 = __shfl_down(A0.x, 1);
        const float lA1 = __shfl_up(A1.y, 1), rA1 = __shfl_down(A1.x, 1);
        const float lA2 = __shfl_up(A2.y, 1), rA2 = __shfl_down(A2.x, 1);
        const float lE0 = __shfl_up(E0.y, 1), rE0 = __shfl_down(E0.x, 1);
        const float lE1 = __shfl_up(E1.y, 1), rE1 = __shfl_down(E1.x, 1);
        const float lE2 = __shfl_up(E2.y, 1), rE2 = __shfl_down(E2.x, 1);

        // -- prefetch NEXT group's taps; latency hides under wgen+combine --
        if (gi < 7) {
            const char* np0 = xbc + (size_t)(2 * (g + 1)) * PLANE_B;
            const char* np1 = np0 + PLANE_B;
            tA0[nxt] = *(const v2f*)(np0 + (size_t)(pb0 + ro0));
            tA1[nxt] = *(const v2f*)(np0 + (size_t)pb0);
            tA2[nxt] = *(const v2f*)(np0 + (size_t)(pb0 + ro2));
            tE0[nxt] = *(const v2f*)(np1 + (size_t)(pb0 + ro0));
            tE1[nxt] = *(const v2f*)(np1 + (size_t)pb0);
            tE2[nxt] = *(const v2f*)(np1 + (size_t)(pb0 + ro2));
        }
        PIN_BATCH();      // next-group tap batch contiguous, above wgen

        // -- fused weight-gen + combine, per k (no wgp array) --
        v2f oA; oA.x = 0.f; oA.y = 0.f;
        v2f oB = oA;
#pragma unroll
        for (int k = 0; k < KK; ++k) {
            const float* w2r = w2 + (g * KK + k) * RMID;  // uniform -> s_load
            const float bb = b2[g * KK + k];
            v2f acc; acc.x = bb; acc.y = bb;
#pragma unroll
            for (int r = 0; r < RMID; ++r) {
                const float w = w2r[r];
                v2f wv; wv.x = w; wv.y = w;
                acc = __builtin_elementwise_fma(wv, t2[r], acc);
            }
            // column-edge masks on this k's weight
            if (k == 0 || k == 3 || k == 6) acc.x *= mL;   // left tap of px0
            if (k == 2 || k == 5 || k == 8) acc.y *= mR;   // right tap of px1

            // tap selection — all constant-folded after unroll
            const v2f Ar = (k < 3) ? A0 : (k < 6) ? A1 : A2;
            const v2f Er = (k < 3) ? E0 : (k < 6) ? E1 : E2;
            const float lA = (k < 3) ? lA0 : (k < 6) ? lA1 : lA2;
            const float rA = (k < 3) ? rA0 : (k < 6) ? rA1 : rA2;
            const float lE = (k < 3) ? lE0 : (k < 6) ? lE1 : lE2;
            const float rE = (k < 3) ? rE0 : (k < 6) ? rE1 : rE2;

            v2f tpA, tpE;
            if (k % 3 == 0)      { tpA.x = lA;   tpA.y = Ar.x;
                                   tpE.x = lE;   tpE.y = Er.x; }
            else if (k % 3 == 1) { tpA = Ar;     tpE = Er;     }
            else                 { tpA.x = Ar.y; tpA.y = rA;
                                   tpE.x = Er.y; tpE.y = rE;   }
            oA = __builtin_elementwise_fma(acc, tpA, oA);
            oB = __builtin_elementwise_fma(acc, tpE, oB);
        }

        __builtin_nontemporal_store(oA, (v2f*)(obc + (size_t)(2 * g)     * PLANE_B + pb0));
        __builtin_nontemporal_store(oB, (v2f*)(obc + (size_t)(2 * g + 1) * PLANE_B + pb0));
    }
}

extern "C" void kernel_launch(void* const* d_in, const int* in_sizes, int n_in,
                              void* d_out, int out_size, void* d_ws, size_t ws_size,
                              hipStream_t stream)
{
    const float* x  = (const float*)d_in[0];
    const float* w1 = (const float*)d_in[1];
    const float* b1 = (const float*)d_in[2];
    const float* pa = (const float*)d_in[3];
    const float* w2 = (const float*)d_in[4];
    const float* b2 = (const float*)d_in[5];
    float* out = (float*)d_out;

    hipLaunchKernelGGL(invol_fused, dim3(1024), dim3(256), 0, stream,
                       x, w1, b1, pa, w2, b2, out);
}

// Round 8
// 128.927 us; speedup vs baseline: 1.0127x; 1.0127x over previous
//
#include <hip/hip_runtime.h>

#define NPIX (128 * 128)
#define CH 64
#define RMID 16
#define KK 9
#define PLANE_B 65536            // bytes per channel plane

typedef float v4f __attribute__((ext_vector_type(4)));

static __device__ __forceinline__ v4f splat4(float s) {
    v4f v; v.x = s; v.y = s; v.z = s; v.w = s; return v;
}

// Fused involution kernel — r15 = r14 resubmit (container failed twice;
// no evidence to update on). Thread = pixel QUAD (v4f).
// Grid 512 = 8 bq (XCD pin, L&7) x 4 group-octets x 16 strips (8 rows);
// block 256 = 8 rows x 32 quad-cols; wave = 2 rows x 32 quads.
// r13 post-mortem: sched_barrier(0) doubled VALUBusy (reg-shuffle copies,
// not allocation) at 56 VGPR — scheduler/RA control is a dead end at 2px/
// thread granularity. Model: wall ~= waves x (issue + nloads x ~250cy) with
// near-zero inter-wave overlap (r11 TLP null). Levers: halve per-px load
// count (v4f 16B loads) and make persistent state so large (t2 = 64 VGPR)
// that the allocator physically cannot collapse to the 52-reg regime.
// (256,2): grid-limited at 2 waves/SIMD, so a 256-VGPR budget costs nothing.
// Shuffle boundary note: wave = 2 rows; lane31<->lane32 cross-row garbage
// lands only on qc==31/qc==0 lanes whose neighbors are image borders —
// masked via lT*=mL / rT*=mR after the shuffle.
__global__ __launch_bounds__(256, 2) void invol_fused(
    const float* __restrict__ x,
    const float* __restrict__ w1,
    const float* __restrict__ b1,
    const float* __restrict__ prelu_a,
    const float* __restrict__ w2,
    const float* __restrict__ b2,
    float* __restrict__ out)
{
    const int qc   = threadIdx.x & 31;    // quad-col: pixels 4qc..4qc+3
    const int rsub = threadIdx.x >> 5;    // row within strip (0..7)

    const int L     = blockIdx.x;         // 0..511
    const int bq    = L & 7;              // batch == XCD pin
    const int go    = (L >> 3) & 3;       // group-octet (consecutive per XCD)
    const int strip = L >> 5;             // 0..15 (8 rows each)

    const int hq  = 8 * strip + rsub;
    const int p0  = hq * 128 + 4 * qc;
    const int pb0 = 4 * p0;               // byte offset, 16B-aligned

    const float* xb  = x + (size_t)bq * CH * NPIX;
    const char*  xbc = (const char*)xb;

    // ---- border masks / clamped row offsets ----
    const float rm0 = (hq > 0)   ? 1.f : 0.f;
    const float rm2 = (hq < 127) ? 1.f : 0.f;
    const float mL  = (qc > 0)   ? 1.f : 0.f;
    const float mR  = (qc < 31)  ? 1.f : 0.f;
    const int   ro0 = (hq > 0)   ? -512 : 0;
    const int   ro2 = (hq < 127) ?  512 : 0;

    // ---- prefetch group 0's 6 taps (v4f): hides under all of conv1 ----
    v4f tA0[2], tA1[2], tA2[2], tE0[2], tE1[2], tE2[2];
    {
        const char* cp0 = xbc + (size_t)(2 * (8 * go)) * PLANE_B;
        const char* cp1 = cp0 + PLANE_B;
        tA0[0] = *(const v4f*)(cp0 + (size_t)(pb0 + ro0));
        tA1[0] = *(const v4f*)(cp0 + (size_t)pb0);
        tA2[0] = *(const v4f*)(cp0 + (size_t)(pb0 + ro2));
        tE0[0] = *(const v4f*)(cp1 + (size_t)(pb0 + ro0));
        tE1[0] = *(const v4f*)(cp1 + (size_t)pb0);
        tE2[0] = *(const v4f*)(cp1 + (size_t)(pb0 + ro2));
    }

    // ---- conv1 (pixel-quad layout), octet double-buffered ----
    v4f t2[RMID];
#pragma unroll
    for (int r = 0; r < RMID; ++r)
        t2[r] = splat4(b1[r]);

    const float* xp = xb + p0;
    v4f xv[2][8];
#pragma unroll
    for (int k = 0; k < 8; ++k)
        xv[0][k] = *(const v4f*)(xp + (size_t)k * NPIX);
#pragma unroll
    for (int oct = 0; oct < 8; ++oct) {
        const int cb = oct & 1, nb = cb ^ 1;       // constant after unroll
        if (oct < 7) {
#pragma unroll
            for (int k = 0; k < 8; ++k)
                xv[nb][k] = *(const v4f*)(xp + (size_t)((oct + 1) * 8 + k) * NPIX);
        }
#pragma unroll
        for (int k = 0; k < 8; ++k) {
#pragma unroll
            for (int r = 0; r < RMID; ++r) {
                const float w = w1[r * CH + oct * 8 + k];   // uniform -> s_load
                t2[r] = __builtin_elementwise_fma(splat4(w), xv[cb][k], t2[r]);
            }
        }
    }
    // PReLU: t = max(t,0) + a*min(t,0)
    {
        const v4f av = splat4(prelu_a[0]);
        const v4f z  = splat4(0.f);
#pragma unroll
        for (int r = 0; r < RMID; ++r) {
            const v4f pos = __builtin_elementwise_max(t2[r], z);
            const v4f neg = __builtin_elementwise_min(t2[r], z);
            t2[r] = __builtin_elementwise_fma(av, neg, pos);
        }
    }

    const v4f rm0v = splat4(rm0);
    const v4f rm2v = splat4(rm2);

    char* obc = (char*)(out + (size_t)bq * CH * NPIX);

#pragma unroll
    for (int gi = 0; gi < 8; ++gi) {
        const int g   = 8 * go + gi;               // block-uniform
        const int cur = gi & 1, nxt = cur ^ 1;     // constant after unroll

        // -- row-mask taps, then shuffle EARLY (lgkm drains under wgen) --
        const v4f A0 = tA0[cur] * rm0v;
        const v4f A1 = tA1[cur];
        const v4f A2 = tA2[cur] * rm2v;
        const v4f E0 = tE0[cur] * rm0v;
        const v4f E1 = tE1[cur];
        const v4f E2 = tE2[cur] * rm2v;

        float lA0 = __shfl_up(A0.w, 1), rA0 = __shfl_down(A0.x, 1);
        float lA1 = __shfl_up(A1.w, 1), rA1 = __shfl_down(A1.x, 1);
        float lA2 = __shfl_up(A2.w, 1), rA2 = __shfl_down(A2.x, 1);
        float lE0 = __shfl_up(E0.w, 1), rE0 = __shfl_down(E0.x, 1);
        float lE1 = __shfl_up(E1.w, 1), rE1 = __shfl_down(E1.x, 1);
        float lE2 = __shfl_up(E2.w, 1), rE2 = __shfl_down(E2.x, 1);
        // mask cross-row/border shuffle garbage (qc==0 / qc==31 lanes)
        lA0 *= mL; lA1 *= mL; lA2 *= mL; lE0 *= mL; lE1 *= mL; lE2 *= mL;
        rA0 *= mR; rA1 *= mR; rA2 *= mR; rE0 *= mR; rE1 *= mR; rE2 *= mR;

        // -- prefetch NEXT group's taps; hides under wgen+combine --
        if (gi < 7) {
            const char* np0 = xbc + (size_t)(2 * (g + 1)) * PLANE_B;
            const char* np1 = np0 + PLANE_B;
            tA0[nxt] = *(const v4f*)(np0 + (size_t)(pb0 + ro0));
            tA1[nxt] = *(const v4f*)(np0 + (size_t)pb0);
            tA2[nxt] = *(const v4f*)(np0 + (size_t)(pb0 + ro2));
            tE0[nxt] = *(const v4f*)(np1 + (size_t)(pb0 + ro0));
            tE1[nxt] = *(const v4f*)(np1 + (size_t)pb0);
            tE2[nxt] = *(const v4f*)(np1 + (size_t)(pb0 + ro2));
        }

        // -- fused weight-gen + combine, per k --
        v4f oA = splat4(0.f);
        v4f oB = splat4(0.f);
#pragma unroll
        for (int k = 0; k < KK; ++k) {
            const float* w2r = w2 + (g * KK + k) * RMID;  // uniform -> s_load
            v4f acc = splat4(b2[g * KK + k]);
#pragma unroll
            for (int r = 0; r < RMID; ++r)
                acc = __builtin_elementwise_fma(splat4(w2r[r]), t2[r], acc);

            // tap selection — constant-folded after unroll
            const v4f Ar = (k < 3) ? A0 : (k < 6) ? A1 : A2;
            const v4f Er = (k < 3) ? E0 : (k < 6) ? E1 : E2;
            const float lA = (k < 3) ? lA0 : (k < 6) ? lA1 : lA2;
            const float rA = (k < 3) ? rA0 : (k < 6) ? rA1 : rA2;
            const float lE = (k < 3) ? lE0 : (k < 6) ? lE1 : lE2;
            const float rE = (k < 3) ? rE0 : (k < 6) ? rE1 : rE2;

            v4f tpA, tpE;
            if (k % 3 == 0) {            // left-shifted taps
                tpA.x = lA;   tpA.y = Ar.x; tpA.z = Ar.y; tpA.w = Ar.z;
                tpE.x = lE;   tpE.y = Er.x; tpE.z = Er.y; tpE.w = Er.z;
            } else if (k % 3 == 1) {     // centered
                tpA = Ar;     tpE = Er;
            } else {                     // right-shifted taps
                tpA.x = Ar.y; tpA.y = Ar.z; tpA.z = Ar.w; tpA.w = rA;
                tpE.x = Er.y; tpE.y = Er.z; tpE.z = Er.w; tpE.w = rE;
            }
            oA = __builtin_elementwise_fma(acc, tpA, oA);
            oB = __builtin_elementwise_fma(acc, tpE, oB);
        }

        __builtin_nontemporal_store(oA, (v4f*)(obc + (size_t)(2 * g)     * PLANE_B + pb0));
        __builtin_nontemporal_store(oB, (v4f*)(obc + (size_t)(2 * g + 1) * PLANE_B + pb0));
    }
}

extern "C" void kernel_launch(void* const* d_in, const int* in_sizes, int n_in,
                              void* d_out, int out_size, void* d_ws, size_t ws_size,
                              hipStream_t stream)
{
    const float* x  = (const float*)d_in[0];
    const float* w1 = (const float*)d_in[1];
    const float* b1 = (const float*)d_in[2];
    const float* pa = (const float*)d_in[3];
    const float* w2 = (const float*)d_in[4];
    const float* b2 = (const float*)d_in[5];
    float* out = (float*)d_out;

    hipLaunchKernelGGL(invol_fused, dim3(512), dim3(256), 0, stream,
                       x, w1, b1, pa, w2, b2, out);
}

// Round 9
// 112.456 us; speedup vs baseline: 1.1610x; 1.1465x over previous
//
#include <hip/hip_runtime.h>

#define NPIX (128 * 128)
#define CH 64
#define RMID 16
#define KK 9
#define PLANE_B 65536            // bytes per channel plane

typedef float v2f __attribute__((ext_vector_type(2)));

// r16: hand-batched inline-asm loads on the r9 base.
// Evidence r8-r15: allocator is a strict minimizer (52/56/76 VGPR); pre-RA
// scheduler sinks every load to its use at MLP~1 (~350-450cy exposed per
// load = 66-75% stall). No source/bounds/sched_barrier variant changed it.
// Inline-asm global_load with "=v" outputs is the one thing RA cannot undo:
// batches stay contiguous (volatile asm ordering), results forced live,
// waits are counted vmcnt(N) (AITER pattern). Conv1: 8x8-load batches,
// dbuf, steady vmcnt(8). Taps: 6-load batches 1 group ahead, vmcnt(6)
// (retires prev taps+2 stores, leaves new 6). Every vmcnt asm is followed
// by sched_barrier(0) (rule #18: consumers must not hoist above the wait).
// All x-loads are asm so compiler vmcnt accounting can't be corrupted
// (it has no vmem loads of its own; nt-stores are drain-tolerant).
#define ASM_LOAD2(dst, voff) \
    asm volatile("global_load_dwordx2 %0, %1, %2" \
                 : "=v"(dst) : "v"((uint32_t)(voff)), "s"(xbc))

#define VMWAIT(N) do { \
    asm volatile("s_waitcnt vmcnt(" #N ")" ::: "memory"); \
    __builtin_amdgcn_sched_barrier(0); \
} while (0)

#define ISSUE8(B, oct) do { \
    const uint32_t c0 = (uint32_t)pb0 + (uint32_t)((oct) * 8) * 65536u; \
    ASM_LOAD2(B##0, c0); \
    ASM_LOAD2(B##1, c0 + 1u * 65536u); \
    ASM_LOAD2(B##2, c0 + 2u * 65536u); \
    ASM_LOAD2(B##3, c0 + 3u * 65536u); \
    ASM_LOAD2(B##4, c0 + 4u * 65536u); \
    ASM_LOAD2(B##5, c0 + 5u * 65536u); \
    ASM_LOAD2(B##6, c0 + 6u * 65536u); \
    ASM_LOAD2(B##7, c0 + 7u * 65536u); \
} while (0)

#define FMA8(xvreg, ch) do { \
    _Pragma("unroll") \
    for (int r = 0; r < RMID; ++r) { \
        const float w = w1[r * CH + (ch)]; \
        v2f wv; wv.x = w; wv.y = w; \
        t2[r] = __builtin_elementwise_fma(wv, (xvreg), t2[r]); \
    } \
} while (0)

#define CONSUME8(B, oct) do { \
    FMA8(B##0, (oct) * 8 + 0); \
    FMA8(B##1, (oct) * 8 + 1); \
    FMA8(B##2, (oct) * 8 + 2); \
    FMA8(B##3, (oct) * 8 + 3); \
    FMA8(B##4, (oct) * 8 + 4); \
    FMA8(B##5, (oct) * 8 + 5); \
    FMA8(B##6, (oct) * 8 + 6); \
    FMA8(B##7, (oct) * 8 + 7); \
} while (0)

#define ISSUE_TAPS(B, gg) do { \
    const uint32_t q0 = (uint32_t)pb0 + (uint32_t)(2 * (gg)) * 65536u; \
    const uint32_t q1 = q0 + 65536u; \
    ASM_LOAD2(B##A0, q0 + (uint32_t)ro0); \
    ASM_LOAD2(B##A1, q0); \
    ASM_LOAD2(B##A2, q0 + (uint32_t)ro2); \
    ASM_LOAD2(B##E0, q1 + (uint32_t)ro0); \
    ASM_LOAD2(B##E1, q1); \
    ASM_LOAD2(B##E2, q1 + (uint32_t)ro2); \
} while (0)

__device__ __forceinline__ void group_tail(
    int g, v2f tA0, v2f tA1, v2f tA2, v2f tE0, v2f tE1, v2f tE2,
    float mL, float mR, v2f rm0v, v2f rm2v,
    const v2f (&t2)[RMID], const float* __restrict__ w2,
    const float* __restrict__ b2, char* obc, int pb0)
{
    // row-mask the taps, then shuffle (lgkm drains under wgen)
    const v2f A0 = tA0 * rm0v;
    const v2f A1 = tA1;
    const v2f A2 = tA2 * rm2v;
    const v2f E0 = tE0 * rm0v;
    const v2f E1 = tE1;
    const v2f E2 = tE2 * rm2v;

    const float lA0 = __shfl_up(A0.y, 1), rA0 = __shfl_down(A0.x, 1);
    const float lA1 = __shfl_up(A1.y, 1), rA1 = __shfl_down(A1.x, 1);
    const float lA2 = __shfl_up(A2.y, 1), rA2 = __shfl_down(A2.x, 1);
    const float lE0 = __shfl_up(E0.y, 1), rE0 = __shfl_down(E0.x, 1);
    const float lE1 = __shfl_up(E1.y, 1), rE1 = __shfl_down(E1.x, 1);
    const float lE2 = __shfl_up(E2.y, 1), rE2 = __shfl_down(E2.x, 1);

    v2f oA; oA.x = 0.f; oA.y = 0.f;
    v2f oB = oA;
#pragma unroll
    for (int k = 0; k < KK; ++k) {
        const float* w2r = w2 + (g * KK + k) * RMID;  // uniform -> s_load
        const float bb = b2[g * KK + k];
        v2f acc; acc.x = bb; acc.y = bb;
#pragma unroll
        for (int r = 0; r < RMID; ++r) {
            const float w = w2r[r];
            v2f wv; wv.x = w; wv.y = w;
            acc = __builtin_elementwise_fma(wv, t2[r], acc);
        }
        if (k == 0 || k == 3 || k == 6) acc.x *= mL;   // left tap of px0
        if (k == 2 || k == 5 || k == 8) acc.y *= mR;   // right tap of px1

        const v2f Ar = (k < 3) ? A0 : (k < 6) ? A1 : A2;
        const v2f Er = (k < 3) ? E0 : (k < 6) ? E1 : E2;
        const float lA = (k < 3) ? lA0 : (k < 6) ? lA1 : lA2;
        const float rA = (k < 3) ? rA0 : (k < 6) ? rA1 : rA2;
        const float lE = (k < 3) ? lE0 : (k < 6) ? lE1 : lE2;
        const float rE = (k < 3) ? rE0 : (k < 6) ? rE1 : rE2;

        v2f tpA, tpE;
        if (k % 3 == 0)      { tpA.x = lA;   tpA.y = Ar.x;
                               tpE.x = lE;   tpE.y = Er.x; }
        else if (k % 3 == 1) { tpA = Ar;     tpE = Er;     }
        else                 { tpA.x = Ar.y; tpA.y = rA;
                               tpE.x = Er.y; tpE.y = rE;   }
        oA = __builtin_elementwise_fma(acc, tpA, oA);
        oB = __builtin_elementwise_fma(acc, tpE, oB);
    }

    __builtin_nontemporal_store(oA, (v2f*)(obc + (size_t)(2 * g)     * PLANE_B + pb0));
    __builtin_nontemporal_store(oB, (v2f*)(obc + (size_t)(2 * g + 1) * PLANE_B + pb0));
}

__global__ __launch_bounds__(256, 2) void invol_fused(
    const float* __restrict__ x,
    const float* __restrict__ w1,
    const float* __restrict__ b1,
    const float* __restrict__ prelu_a,
    const float* __restrict__ w2,
    const float* __restrict__ b2,
    float* __restrict__ out)
{
    const int c    = threadIdx.x & 63;    // column-pair id (cols 2c, 2c+1)
    const int rsub = threadIdx.x >> 6;    // row within strip, wave-uniform

    const int L     = blockIdx.x;         // 0..1023
    const int bq    = L & 7;              // batch == XCD pin
    const int go    = (L >> 3) & 3;       // group-octet (consecutive per XCD)
    const int strip = L >> 5;             // 0..31 (4 rows)

    const int hq  = 4 * strip + rsub;
    const int p0  = hq * 128 + 2 * c;
    const int pb0 = 4 * p0;

    const float* xb  = x + (size_t)bq * CH * NPIX;
    const char*  xbc = (const char*)xb;   // SGPR base for all asm loads

    const float rm0 = (hq > 0)   ? 1.f : 0.f;
    const float rm2 = (hq < 127) ? 1.f : 0.f;
    const float mL  = (c > 0)    ? 1.f : 0.f;
    const float mR  = (c < 63)   ? 1.f : 0.f;
    const int   ro0 = (hq > 0)   ? -512 : 0;
    const int   ro2 = (hq < 127) ?  512 : 0;

    // asm-owned load destinations (forced live by "=v" outputs)
    v2f xA0, xA1, xA2, xA3, xA4, xA5, xA6, xA7;
    v2f xB0, xB1, xB2, xB3, xB4, xB5, xB6, xB7;
    v2f taA0, taA1, taA2, taE0, taE1, taE2;
    v2f tbA0, tbA1, tbA2, tbE0, tbE1, tbE2;

    // ---- issue: group-0 taps (6) + conv1 octets 0,1 (16) -> 22 in flight --
    ISSUE_TAPS(ta, 8 * go + 0);
    ISSUE8(xA, 0);
    ISSUE8(xB, 1);

    v2f t2[RMID];
#pragma unroll
    for (int r = 0; r < RMID; ++r) {
        const float b = b1[r];
        t2[r].x = b; t2[r].y = b;
    }

    // ---- conv1: consume/issue ladder, steady-state vmcnt(8) ----
    VMWAIT(8);  CONSUME8(xA, 0); ISSUE8(xA, 2);   // retires taps0 + oct0
    VMWAIT(8);  CONSUME8(xB, 1); ISSUE8(xB, 3);
    VMWAIT(8);  CONSUME8(xA, 2); ISSUE8(xA, 4);
    VMWAIT(8);  CONSUME8(xB, 3); ISSUE8(xB, 5);
    VMWAIT(8);  CONSUME8(xA, 4); ISSUE8(xA, 6);
    VMWAIT(8);  CONSUME8(xB, 5); ISSUE8(xB, 7);
    VMWAIT(8);  CONSUME8(xA, 6);
    VMWAIT(0);  CONSUME8(xB, 7);

    // PReLU: t = max(t,0) + a*min(t,0)
    {
        const float a = prelu_a[0];
        v2f av; av.x = a; av.y = a;
        v2f z;  z.x = 0.f; z.y = 0.f;
#pragma unroll
        for (int r = 0; r < RMID; ++r) {
            const v2f pos = __builtin_elementwise_max(t2[r], z);
            const v2f neg = __builtin_elementwise_min(t2[r], z);
            t2[r] = __builtin_elementwise_fma(av, neg, pos);
        }
    }

    v2f rm0v; rm0v.x = rm0; rm0v.y = rm0;
    v2f rm2v; rm2v.x = rm2; rm2v.y = rm2;

    char* obc = (char*)(out + (size_t)bq * CH * NPIX);
    const int g0 = 8 * go;

    // ---- group ladder: issue next taps, vmcnt(6) (retires prev taps +
    //      2 prev stores, leaves the 6 just issued), consume current ----
    ISSUE_TAPS(tb, g0 + 1); VMWAIT(6);
    group_tail(g0 + 0, taA0, taA1, taA2, taE0, taE1, taE2, mL, mR, rm0v, rm2v, t2, w2, b2, obc, pb0);
    ISSUE_TAPS(ta, g0 + 2); VMWAIT(6);
    group_tail(g0 + 1, tbA0, tbA1, tbA2, tbE0, tbE1, tbE2, mL, mR, rm0v, rm2v, t2, w2, b2, obc, pb0);
    ISSUE_TAPS(tb, g0 + 3); VMWAIT(6);
    group_tail(g0 + 2, taA0, taA1, taA2, taE0, taE1, taE2, mL, mR, rm0v, rm2v, t2, w2, b2, obc, pb0);
    ISSUE_TAPS(ta, g0 + 4); VMWAIT(6);
    group_tail(g0 + 3, tbA0, tbA1, tbA2, tbE0, tbE1, tbE2, mL, mR, rm0v, rm2v, t2, w2, b2, obc, pb0);
    ISSUE_TAPS(tb, g0 + 5); VMWAIT(6);
    group_tail(g0 + 4, taA0, taA1, taA2, taE0, taE1, taE2, mL, mR, rm0v, rm2v, t2, w2, b2, obc, pb0);
    ISSUE_TAPS(ta, g0 + 6); VMWAIT(6);
    group_tail(g0 + 5, tbA0, tbA1, tbA2, tbE0, tbE1, tbE2, mL, mR, rm0v, rm2v, t2, w2, b2, obc, pb0);
    ISSUE_TAPS(tb, g0 + 7); VMWAIT(6);
    group_tail(g0 + 6, taA0, taA1, taA2, taE0, taE1, taE2, mL, mR, rm0v, rm2v, t2, w2, b2, obc, pb0);
    VMWAIT(2);  // retires g7 taps (oldest); leaves only g6 stores
    group_tail(g0 + 7, tbA0, tbA1, tbA2, tbE0, tbE1, tbE2, mL, mR, rm0v, rm2v, t2, w2, b2, obc, pb0);
}

extern "C" void kernel_launch(void* const* d_in, const int* in_sizes, int n_in,
                              void* d_out, int out_size, void* d_ws, size_t ws_size,
                              hipStream_t stream)
{
    const float* x  = (const float*)d_in[0];
    const float* w1 = (const float*)d_in[1];
    const float* b1 = (const float*)d_in[2];
    const float* pa = (const float*)d_in[3];
    const float* w2 = (const float*)d_in[4];
    const float* b2 = (const float*)d_in[5];
    float* out = (float*)d_out;

    hipLaunchKernelGGL(invol_fused, dim3(1024), dim3(256), 0, stream,
                       x, w1, b1, pa, w2, b2, out);
}